// Round 2
// baseline (538.035 us; speedup 1.0000x reference)
//
#include <hip/hip_runtime.h>
#include <hip/hip_bf16.h>

typedef __bf16 bf16x8 __attribute__((ext_vector_type(8)));
typedef float  f32x4  __attribute__((ext_vector_type(4)));

#define LDST 56  // LDS row stride (elements): 112B = 7*16B aligned, benign 2-way conflicts

// ---------------- build x_in(bf16) = [kg_emb[node_id] | ccle_mlp(ccle)[node_id]] ----------------
__global__ __launch_bounds__(256) void build_x_kernel(
    const float* __restrict__ kg_emb, const float* __restrict__ ccle,
    const float* __restrict__ cw1, const float* __restrict__ cb1,
    const float* __restrict__ cw2, const float* __restrict__ cb2,
    const int* __restrict__ node_id, __bf16* __restrict__ x_in, int Nn)
{
    __shared__ float h[2][32];
    int sub = threadIdx.x >> 7;       // 2 nodes per block
    int t   = threadIdx.x & 127;
    int i   = blockIdx.x * 2 + sub;
    if (i < Nn && t < 32) {
        int kid = node_id[i];
        float a = 0.f;
        #pragma unroll
        for (int j = 0; j < 4; j++) a += ccle[kid*4 + j] * cw1[j*32 + t];
        a += cb1[t];
        h[sub][t] = a < 0.f ? 0.01f * a : a;
    }
    __syncthreads();
    if (i < Nn) {
        int kid = node_id[i];
        x_in[i*256 + t] = (__bf16)kg_emb[kid*128 + t];
        float a = 0.f;
        #pragma unroll
        for (int j = 0; j < 32; j++) a += h[sub][j] * cw2[j*128 + t];
        a += cb2[t];
        x_in[i*256 + 128 + t] = (__bf16)a;
    }
}

// ---------------- CSR build ----------------
__global__ void hist_kernel(const int* __restrict__ ei, int* __restrict__ deg, int E) {
    int e = blockIdx.x * 256 + threadIdx.x;
    if (e < E) atomicAdd(&deg[ei[E + e]], 1);
}

__global__ __launch_bounds__(1024) void scan_kernel(
    const int* __restrict__ deg, int* __restrict__ row_off, int* __restrict__ cursor, int Nn)
{
    __shared__ int wsum[16];
    __shared__ int carry_s;
    int t = threadIdx.x;
    int lane = t & 63, wid = t >> 6;
    if (t == 0) carry_s = 0;
    __syncthreads();
    for (int base = 0; base < Nn; base += 1024) {
        int idx = base + t;
        int v = (idx < Nn) ? deg[idx] : 0;
        int incl = v;
        #pragma unroll
        for (int off = 1; off < 64; off <<= 1) {
            int x = __shfl_up(incl, off, 64);
            if (lane >= off) incl += x;
        }
        if (lane == 63) wsum[wid] = incl;
        __syncthreads();
        if (wid == 0) {
            int wv = (lane < 16) ? wsum[lane] : 0;
            #pragma unroll
            for (int off = 1; off < 16; off <<= 1) {
                int x = __shfl_up(wv, off, 64);
                if (lane >= off) wv += x;
            }
            if (lane < 16) wsum[lane] = wv;
        }
        __syncthreads();
        int wprefix = (wid > 0) ? wsum[wid - 1] : 0;
        int excl = carry_s + wprefix + incl - v;
        if (idx < Nn) { row_off[idx] = excl; cursor[idx] = excl; }
        __syncthreads();
        if (t == 1023) carry_s += wsum[15];
        __syncthreads();
    }
    if (t == 0) row_off[Nn] = carry_s;
}

__global__ void scatter_kernel(const int* __restrict__ ei, const int* __restrict__ et,
                               int* __restrict__ cursor, int* __restrict__ cidx, int E) {
    int e = blockIdx.x * 256 + threadIdx.x;
    if (e < E) {
        int d = ei[E + e];
        int pos = atomicAdd(&cursor[d], 1);
        cidx[pos] = (et[e] << 20) | ei[e];   // src < 2^20, et < 8
    }
}

// ---------------- 64x64-tile transpose + fp32->bf16 convert ----------------
__global__ __launch_bounds__(256) void transpose_kernel(
    const float* __restrict__ B, __bf16* __restrict__ Bt)
{
    __shared__ __bf16 tile[64][65];
    int z = blockIdx.z;
    int kb = blockIdx.x * 64;
    int nb = blockIdx.y * 64;
    int t = threadIdx.x;
    const float* Bz = B + z * 65536;
    __bf16* Btz = Bt + z * 65536;
    for (int idx = t; idx < 4096; idx += 256) {
        int rr = idx >> 6, cc = idx & 63;
        tile[rr][cc] = (__bf16)Bz[(kb + rr) * 256 + nb + cc];
    }
    __syncthreads();
    for (int idx = t; idx < 4096; idx += 256) {
        int rr = idx >> 6, cc = idx & 63;
        Btz[(nb + rr) * 256 + kb + cc] = tile[cc][rr];
    }
}

// ---------------- bf16 MFMA GEMM: C[z] = A[z][M][256] @ Bt[z][256][256]^T ----------------
// Bt is [N][K] bf16. bias fp32 optional; leaky slope (1.0 = identity).
// Output: Cb16 (bf16) or Cf32 (fp32) — exactly one non-null.
__global__ __launch_bounds__(256, 2) void gemm_bt_kernel(
    const __bf16* __restrict__ A, long aStride,
    const __bf16* __restrict__ Bt, long bStride,
    __bf16* __restrict__ Cb16, float* __restrict__ Cf32, long cStride,
    const float* __restrict__ bias, float slope, int M)
{
    __shared__ __bf16 As[128 * LDST];
    __shared__ __bf16 Bs[128 * LDST];
    const int z = blockIdx.z;
    const __bf16* Ab = A + z * aStride;
    const __bf16* Bb = Bt + z * bStride;
    const int m0 = blockIdx.x * 128, n0 = blockIdx.y * 128;
    const int t = threadIdx.x;
    const int wave = t >> 6, lane = t & 63;
    const int wy = (wave >> 1) * 64, wx = (wave & 1) * 64;
    const int lr = lane & 15, lq = lane >> 4;
    f32x4 acc[4][4];
    #pragma unroll
    for (int a_ = 0; a_ < 4; a_++)
        #pragma unroll
        for (int b_ = 0; b_ < 4; b_++) acc[a_][b_] = (f32x4){0.f, 0.f, 0.f, 0.f};

    for (int k0 = 0; k0 < 256; k0 += 32) {
        #pragma unroll
        for (int v = 0; v < 2; v++) {
            int chunk = t + v * 256;       // 0..511
            int row = chunk >> 2;          // 0..127
            int kc = (chunk & 3) << 3;     // 0,8,16,24
            uint4 av = {0u, 0u, 0u, 0u};
            int gr = m0 + row;
            if (gr < M) av = *(const uint4*)(Ab + (long)gr * 256 + k0 + kc);
            *(uint4*)(As + row * LDST + kc) = av;
            uint4 bv = *(const uint4*)(Bb + (n0 + row) * 256 + k0 + kc);
            *(uint4*)(Bs + row * LDST + kc) = bv;
        }
        __syncthreads();
        bf16x8 af[4], bfr[4];
        #pragma unroll
        for (int tm = 0; tm < 4; tm++)
            af[tm] = *(const bf16x8*)(As + (wy + tm * 16 + lr) * LDST + lq * 8);
        #pragma unroll
        for (int tn = 0; tn < 4; tn++)
            bfr[tn] = *(const bf16x8*)(Bs + (wx + tn * 16 + lr) * LDST + lq * 8);
        #pragma unroll
        for (int tm = 0; tm < 4; tm++)
            #pragma unroll
            for (int tn = 0; tn < 4; tn++)
                acc[tm][tn] = __builtin_amdgcn_mfma_f32_16x16x32_bf16(af[tm], bfr[tn], acc[tm][tn], 0, 0, 0);
        __syncthreads();
    }
    #pragma unroll
    for (int tm = 0; tm < 4; tm++) {
        #pragma unroll
        for (int tn = 0; tn < 4; tn++) {
            int col = n0 + wx + tn * 16 + lr;
            float bcol = bias ? bias[col] : 0.f;
            #pragma unroll
            for (int ii = 0; ii < 4; ii++) {
                int rg = m0 + wy + tm * 16 + lq * 4 + ii;
                if (rg < M) {
                    float v = acc[tm][tn][ii] + bcol;
                    v = v < 0.f ? v * slope : v;
                    long idx = z * cStride + (long)rg * 256 + col;
                    if (Cb16) Cb16[idx] = (__bf16)v;
                    else      Cf32[idx] = v;
                }
            }
        }
    }
}

// ---------------- s_q[r,n,h] = xw[r,n,:]@q[:,h], s_k likewise ----------------
__global__ __launch_bounds__(256) void sqk_kernel(
    const __bf16* __restrict__ XW, const float* __restrict__ q,
    const float* __restrict__ k, float* __restrict__ s_q,
    float* __restrict__ s_k, int Nn)
{
    __shared__ float qk[8][260];
    int t = threadIdx.x;
    for (int idx = t; idx < 2048; idx += 256) {
        int h8 = idx & 7, kk = idx >> 3;
        qk[h8][kk] = (h8 < 4) ? q[kk * 4 + h8] : k[kk * 4 + (h8 - 4)];
    }
    __syncthreads();
    int r = blockIdx.y;
    int node = blockIdx.x * 32 + (t >> 3);
    int h8 = t & 7;
    if (node >= Nn) return;
    const __bf16* row = XW + ((long)r * Nn + node) * 256;
    float acc = 0.f;
    for (int kb = 0; kb < 256; kb += 8) {
        uint4 pv = *(const uint4*)(row + kb);
        const __bf16* pp = (const __bf16*)&pv;
        #pragma unroll
        for (int j = 0; j < 8; j++) acc += (float)pp[j] * qk[h8][kb + j];
    }
    if (h8 < 4) s_q[((long)r * Nn + node) * 4 + h8] = acc;
    else        s_k[((long)r * Nn + node) * 4 + (h8 - 4)] = acc;
}

// ---------------- per-node attention softmax + weighted aggregation (one wave per node) ----------------
__global__ __launch_bounds__(256) void agg_kernel(
    const __bf16* __restrict__ XW, const float* __restrict__ s_q,
    const float* __restrict__ s_k, const int* __restrict__ row_off,
    const int* __restrict__ cidx, const float* __restrict__ bias,
    const float* __restrict__ skipb, __bf16* __restrict__ outb,
    float* __restrict__ outf, float slope, int Nn)
{
    int lane = threadIdx.x & 63;
    int i = blockIdx.x * 4 + (threadIdx.x >> 6);
    if (i >= Nn) return;
    int base = row_off[i];
    int deg = row_off[i + 1] - base;

    // pass 1: per-head max of leaky(0.2) logits
    float m0 = -3.0e38f, m1 = -3.0e38f, m2 = -3.0e38f, m3 = -3.0e38f;
    for (int e = lane; e < deg; e += 64) {
        int c = cidx[base + e];
        int src = c & 0xFFFFF, et = c >> 20;
        const float* sq = s_q + ((long)et * Nn + i) * 4;
        const float* sk = s_k + ((long)et * Nn + src) * 4;
        float l0 = sq[0] + sk[0]; l0 = l0 < 0.f ? 0.2f * l0 : l0;
        float l1 = sq[1] + sk[1]; l1 = l1 < 0.f ? 0.2f * l1 : l1;
        float l2 = sq[2] + sk[2]; l2 = l2 < 0.f ? 0.2f * l2 : l2;
        float l3 = sq[3] + sk[3]; l3 = l3 < 0.f ? 0.2f * l3 : l3;
        m0 = fmaxf(m0, l0); m1 = fmaxf(m1, l1); m2 = fmaxf(m2, l2); m3 = fmaxf(m3, l3);
    }
    #pragma unroll
    for (int off = 32; off >= 1; off >>= 1) {
        m0 = fmaxf(m0, __shfl_xor(m0, off, 64));
        m1 = fmaxf(m1, __shfl_xor(m1, off, 64));
        m2 = fmaxf(m2, __shfl_xor(m2, off, 64));
        m3 = fmaxf(m3, __shfl_xor(m3, off, 64));
    }

    // pass 2: exp + unnormalized weighted sum (lane = output dim within head)
    float a0 = 0.f, a1 = 0.f, a2 = 0.f, a3 = 0.f;
    float ss0 = 0.f, ss1 = 0.f, ss2 = 0.f, ss3 = 0.f;
    for (int c0 = 0; c0 < deg; c0 += 64) {
        int e = c0 + lane;
        float p0 = 0.f, p1 = 0.f, p2 = 0.f, p3 = 0.f;
        int cc = 0;
        if (e < deg) {
            cc = cidx[base + e];
            int src = cc & 0xFFFFF, et = cc >> 20;
            const float* sq = s_q + ((long)et * Nn + i) * 4;
            const float* sk = s_k + ((long)et * Nn + src) * 4;
            float l0 = sq[0] + sk[0]; l0 = l0 < 0.f ? 0.2f * l0 : l0;
            float l1 = sq[1] + sk[1]; l1 = l1 < 0.f ? 0.2f * l1 : l1;
            float l2 = sq[2] + sk[2]; l2 = l2 < 0.f ? 0.2f * l2 : l2;
            float l3 = sq[3] + sk[3]; l3 = l3 < 0.f ? 0.2f * l3 : l3;
            p0 = __expf(l0 - m0); p1 = __expf(l1 - m1);
            p2 = __expf(l2 - m2); p3 = __expf(l3 - m3);
        }
        ss0 += p0; ss1 += p1; ss2 += p2; ss3 += p3;
        int cnt = min(64, deg - c0);
        for (int j = 0; j < cnt; j++) {
            float q0 = __shfl(p0, j, 64);
            float q1 = __shfl(p1, j, 64);
            float q2 = __shfl(p2, j, 64);
            float q3 = __shfl(p3, j, 64);
            int cj = __shfl(cc, j, 64);
            int src = cj & 0xFFFFF, et = cj >> 20;
            const __bf16* xr = XW + ((long)et * Nn + src) * 256;
            a0 += q0 * (float)xr[lane];
            a1 += q1 * (float)xr[64 + lane];
            a2 += q2 * (float)xr[128 + lane];
            a3 += q3 * (float)xr[192 + lane];
        }
    }
    #pragma unroll
    for (int off = 32; off >= 1; off >>= 1) {
        ss0 += __shfl_xor(ss0, off, 64);
        ss1 += __shfl_xor(ss1, off, 64);
        ss2 += __shfl_xor(ss2, off, 64);
        ss3 += __shfl_xor(ss3, off, 64);
    }
    float i0 = 1.f / fmaxf(ss0, 1e-16f);
    float i1 = 1.f / fmaxf(ss1, 1e-16f);
    float i2 = 1.f / fmaxf(ss2, 1e-16f);
    float i3 = 1.f / fmaxf(ss3, 1e-16f);

    float v0 = a0 * i0 + bias[lane];
    float v1 = a1 * i1 + bias[64 + lane];
    float v2 = a2 * i2 + bias[128 + lane];
    float v3 = a3 * i3 + bias[192 + lane];
    if (skipb) {
        v0 += skipb[(long)i * 256 + lane];
        v1 += skipb[(long)i * 256 + 64 + lane];
        v2 += skipb[(long)i * 256 + 128 + lane];
        v3 += skipb[(long)i * 256 + 192 + lane];
    }
    v0 = v0 < 0.f ? slope * v0 : v0;
    v1 = v1 < 0.f ? slope * v1 : v1;
    v2 = v2 < 0.f ? slope * v2 : v2;
    v3 = v3 < 0.f ? slope * v3 : v3;
    if (outb) {
        outb[(long)i * 256 + lane]       = (__bf16)v0;
        outb[(long)i * 256 + 64 + lane]  = (__bf16)v1;
        outb[(long)i * 256 + 128 + lane] = (__bf16)v2;
        outb[(long)i * 256 + 192 + lane] = (__bf16)v3;
    } else {
        outf[(long)i * 256 + lane]       = v0;
        outf[(long)i * 256 + 64 + lane]  = v1;
        outf[(long)i * 256 + 128 + lane] = v2;
        outf[(long)i * 256 + 192 + lane] = v3;
    }
}

extern "C" void kernel_launch(void* const* d_in, const int* in_sizes, int n_in,
                              void* d_out, int out_size, void* d_ws, size_t ws_size,
                              hipStream_t stream)
{
    const float* kg_emb  = (const float*)d_in[0];
    const float* ccle    = (const float*)d_in[1];
    const int*   node_id = (const int*)d_in[2];
    const int*   edge_ix = (const int*)d_in[3];
    const int*   edge_ty = (const int*)d_in[4];
    const float* ccle_w1 = (const float*)d_in[5];
    const float* ccle_b1 = (const float*)d_in[6];
    const float* ccle_w2 = (const float*)d_in[7];
    const float* ccle_b2 = (const float*)d_in[8];
    const float* w1      = (const float*)d_in[9];
    const float* q1      = (const float*)d_in[10];
    const float* k1      = (const float*)d_in[11];
    const float* bias1   = (const float*)d_in[12];
    const float* w2      = (const float*)d_in[13];
    const float* q2      = (const float*)d_in[14];
    const float* k2      = (const float*)d_in[15];
    const float* bias2   = (const float*)d_in[16];
    const float* skip_w1 = (const float*)d_in[17];
    const float* skip_b1 = (const float*)d_in[18];
    const float* skip_w2 = (const float*)d_in[19];
    const float* skip_b2 = (const float*)d_in[20];

    const int Nn = in_sizes[2];
    const int E  = in_sizes[4];
    const int R  = in_sizes[9] / (256 * 256);

    // workspace carve
    char* p = (char*)d_ws;
    auto alloc = [&](size_t bytes) { char* r = p; p += (bytes + 255) & ~(size_t)255; return r; };
    __bf16* x_in  = (__bf16*)alloc((size_t)Nn * 256 * 2);
    __bf16* x1    = (__bf16*)alloc((size_t)Nn * 256 * 2);
    __bf16* sh    = (__bf16*)alloc((size_t)Nn * 256 * 2);
    float*  skipb = (float*)alloc((size_t)Nn * 256 * 4);
    __bf16* XW    = (__bf16*)alloc((size_t)R * Nn * 256 * 2);
    float*  s_q   = (float*)alloc((size_t)R * Nn * 4 * 4);
    float*  s_k   = (float*)alloc((size_t)R * Nn * 4 * 4);
    __bf16* w1t   = (__bf16*)alloc((size_t)R * 65536 * 2);
    __bf16* w2t   = (__bf16*)alloc((size_t)R * 65536 * 2);
    __bf16* sw1t  = (__bf16*)alloc((size_t)65536 * 2);
    __bf16* sw2t  = (__bf16*)alloc((size_t)65536 * 2);
    int* deg     = (int*)alloc((size_t)Nn * 4);
    int* row_off = (int*)alloc((size_t)(Nn + 1) * 4);
    int* cursor  = (int*)alloc((size_t)Nn * 4);
    int* cidx    = (int*)alloc((size_t)E * 4);

    const int mb = (Nn + 127) / 128;
    const int eb = (E + 255) / 256;

    (void)hipMemsetAsync(deg, 0, (size_t)Nn * 4, stream);
    build_x_kernel<<<dim3((Nn + 1) / 2), 256, 0, stream>>>(
        kg_emb, ccle, ccle_w1, ccle_b1, ccle_w2, ccle_b2, node_id, x_in, Nn);
    hist_kernel<<<dim3(eb), 256, 0, stream>>>(edge_ix, deg, E);
    scan_kernel<<<dim3(1), 1024, 0, stream>>>(deg, row_off, cursor, Nn);
    scatter_kernel<<<dim3(eb), 256, 0, stream>>>(edge_ix, edge_ty, cursor, cidx, E);
    transpose_kernel<<<dim3(4, 4, R), 256, 0, stream>>>(w1, w1t);
    transpose_kernel<<<dim3(4, 4, R), 256, 0, stream>>>(w2, w2t);
    transpose_kernel<<<dim3(4, 4, 1), 256, 0, stream>>>(skip_w1, sw1t);
    transpose_kernel<<<dim3(4, 4, 1), 256, 0, stream>>>(skip_w2, sw2t);

    // layer 1: xw1 = x_in @ w1[r]
    gemm_bt_kernel<<<dim3(mb, 2, R), 256, 0, stream>>>(
        x_in, 0L, w1t, 65536L, XW, nullptr, (long)Nn * 256, nullptr, 1.0f, Nn);
    sqk_kernel<<<dim3((Nn + 31) / 32, R), 256, 0, stream>>>(XW, q1, k1, s_q, s_k, Nn);
    agg_kernel<<<dim3((Nn + 3) / 4), 256, 0, stream>>>(
        XW, s_q, s_k, row_off, cidx, bias1, nullptr, x1, nullptr, 0.01f, Nn);

    // skip path: skip = lrelu(x_in@skip_w1+b1)@skip_w2+b2
    gemm_bt_kernel<<<dim3(mb, 2, 1), 256, 0, stream>>>(
        x_in, 0L, sw1t, 0L, sh, nullptr, 0L, skip_b1, 0.01f, Nn);
    gemm_bt_kernel<<<dim3(mb, 2, 1), 256, 0, stream>>>(
        sh, 0L, sw2t, 0L, nullptr, skipb, 0L, skip_b2, 1.0f, Nn);

    // layer 2: xw2 = x1 @ w2[r]
    gemm_bt_kernel<<<dim3(mb, 2, R), 256, 0, stream>>>(
        x1, 0L, w2t, 65536L, XW, nullptr, (long)Nn * 256, nullptr, 1.0f, Nn);
    sqk_kernel<<<dim3((Nn + 31) / 32, R), 256, 0, stream>>>(XW, q2, k2, s_q, s_k, Nn);
    agg_kernel<<<dim3((Nn + 3) / 4), 256, 0, stream>>>(
        XW, s_q, s_k, row_off, cidx, bias2, skipb, nullptr, (float*)d_out, 0.01f, Nn);
}